// Round 4
// baseline (657.380 us; speedup 1.0000x reference)
//
#include <hip/hip_runtime.h>
#include <cstdint>

typedef unsigned short u16;
typedef __attribute__((ext_vector_type(8))) short short8;
typedef __attribute__((ext_vector_type(4))) float floatx4;

#define BAR()      __builtin_amdgcn_s_barrier()
#define SCHEDBAR() __builtin_amdgcn_sched_barrier(0)

__device__ __forceinline__ u16 f2bf(float f) {
    unsigned u = __float_as_uint(f);
    u += 0x7FFFu + ((u >> 16) & 1u);
    return (u16)(u >> 16);
}

__device__ __forceinline__ void async16(const void* g, void* l) {
    __builtin_amdgcn_global_load_lds(
        (const __attribute__((address_space(1))) unsigned*)g,
        (__attribute__((address_space(3))) unsigned*)l, 16, 0, 0);
}

// ---------------- cast fp32 -> bf16, 8 elems/thread ----------------
__global__ void cast_bf16_kernel(const float* __restrict__ in, u16* __restrict__ out, long n8) {
    long i = (long)blockIdx.x * 256 + threadIdx.x;
    if (i >= n8) return;
    const float4* p = (const float4*)in;
    float4 a = p[i * 2], b = p[i * 2 + 1];
    uint4 o;
    o.x = f2bf(a.x) | ((unsigned)f2bf(a.y) << 16);
    o.y = f2bf(a.z) | ((unsigned)f2bf(a.w) << 16);
    o.z = f2bf(b.x) | ((unsigned)f2bf(b.y) << 16);
    o.w = f2bf(b.z) | ((unsigned)f2bf(b.w) << 16);
    ((uint4*)out)[i] = o;
}

// ---------------- zero fill (uint4 granularity) ----------------
__global__ void fill_zero(uint4* __restrict__ p, int n) {
    int i = blockIdx.x * 256 + threadIdx.x;
    if (i < n) p[i] = (uint4){0u, 0u, 0u, 0u};
}

// ---------------- transpose + cast: W[K][N] -> Wt[N][K] bf16 ----------------
__global__ void transpose_cast(const float* __restrict__ W, u16* __restrict__ Wt, int K, int N) {
    __shared__ float tile[32][33];
    int bx = blockIdx.x * 32, by = blockIdx.y * 32;
    int tx = threadIdx.x, ty = threadIdx.y;
#pragma unroll
    for (int i = 0; i < 32; i += 8)
        tile[ty + i][tx] = W[(long)(by + ty + i) * N + bx + tx];
    __syncthreads();
#pragma unroll
    for (int i = 0; i < 32; i += 8)
        Wt[(long)(bx + ty + i) * K + by + tx] = f2bf(tile[tx][ty + i]);
}

// ============ 8-phase 256x256 GEMM (T1+T2+T3+T4+T5), M=32768 N=1280(pad) K=1152 ============
// C[M][1152] = A[M][1152] @ Bt[1280][1152]^T   (Bt rows 1152..1279 zero)
// 8 waves (2Mx4N), BK=64, 128KiB dynamic LDS (2 tile-buffers, A+B).
// Skeleton per phase (m201-verified): {ds_reads + staging} SCHEDBAR BAR lgkmcnt(0)
// SCHEDBAR prio1 MFMA prio0 [vmcnt(N)] SCHEDBAR BAR. No "memory" clobbers anywhere in
// the loop: barriers don't force lgkm/vmcnt(0) drains (R2's serializer); counted waits
// are per-wave. sched_barrier(0) at every boundary pins program order (rule #18:
// bare waitcnt asm does NOT order register-only MFMA or LDS reads by itself).
// Hazard ledger (per-wave, 2 loads/half-stage, 8 staged loads/iter):
//  - end-P4 vmcnt(12): A0,B0(T+1) landed before P1 reads them
//    [after A0,B0(T+1): A1,B1(T+1)=4 + iter-T stages 8 = 12]
//  - end-P1 vmcnt(10): A1(T) landed before P2 reads [B1(T)=2 + iter-(T-1) 8 = 10]
//  - end-P2 vmcnt(12): B1(T) landed before P3 reads [iter-(T-1) 8 + P2-of-T 4 = 12]
//  - overwrite-safety: each half-slot staged in phase k is last ds_read in phase k-1;
//    readers' MFMAs (which force the reads complete) precede their barrier arrival,
//    so the slot is dead CU-wide when staging issues one barrier later.
// MODE 0: bf16 out, (acc+bias)*scale.  MODE 2: fp32 out.
template <int MODE>
__global__ __launch_bounds__(512, 2)
void gemm8p(const u16* __restrict__ A, const u16* __restrict__ Bt,
            const float* __restrict__ bias, float scale,
            u16* __restrict__ outA, float* __restrict__ outF) {
    extern __shared__ u16 smem[];   // [0,32768): A bufs; [32768,65536): B bufs
    const int K = 1152;
    const int tid = threadIdx.x, lane = tid & 63, wave = tid >> 6;
    const int quad = lane >> 4, cl = lane & 15;
    const int wm = wave >> 2, wn = wave & 3;
    const int l3 = lane >> 3, l7 = lane & 7;

    // T1: bijective XCD swizzle (640 = 8*80), col-fastest decode
    int bid = blockIdx.x;
    int swz = (bid & 7) * 80 + (bid >> 3);
    int colTile = swz % 5, rowTile = swz / 5;
    const long rowBase = (long)rowTile * 256;
    const int colBase = colTile * 256;

    // staging source pointers (pre-swizzled granule)
    const int sg = (l7 ^ l3) * 8;
    const u16* pA = A + (rowBase + (wave >> 2) * 128 + (wave & 3) * 16 + l3) * (long)K + sg;
    const u16* pB = Bt + ((long)colBase + (wave >> 1) * 64 + (wave & 1) * 16 + l3) * (long)K + sg;
    const int dA0 = ((wave >> 2) * 128 + (wave & 3) * 16) * 64;
    const int dB0 = ((wave >> 1) * 64 + (wave & 1) * 16) * 64;

    auto stA = [&](int Ts, int h) {
        const u16* s = pA + (long)(h * 64) * K + Ts * 64;
        int d = (Ts & 1) * 16384 + dA0 + h * 4096;
        async16(s, &smem[d]);
        async16(s + 8 * K, &smem[d + 512]);
    };
    auto stB = [&](int Ts, int h) {
        const u16* s = pB + (long)(h * 32) * K + Ts * 64;
        int d = 32768 + (Ts & 1) * 16384 + dB0 + h * 2048;
        async16(s, &smem[d]);
        async16(s + 8 * K, &smem[d + 512]);
    };

    // fragment read offsets (T2 swizzled granule: row&7 == cl&7)
    const int arow = wm * 8192 + cl * 64;
    const int brow = wn * 4096 + cl * 64;
    const int gs[2] = {((quad) ^ (cl & 7)) * 8, ((4 + quad) ^ (cl & 7)) * 8};

    floatx4 acc[8][4];
#pragma unroll
    for (int i = 0; i < 8; i++)
#pragma unroll
        for (int j = 0; j < 4; j++) acc[i][j] = (floatx4){0.f, 0.f, 0.f, 0.f};

    // prologue: stage tiles 0,1 fully (order per tile: A0,B0,A1,B1)
#pragma unroll
    for (int Ts = 0; Ts < 2; ++Ts) {
        stA(Ts, 0); stB(Ts, 0); stA(Ts, 1); stB(Ts, 1);
    }
    SCHEDBAR();
    // need A0,B0(0) landed: issued-after = A1,B1(0) + tile1's 4 halves = 12
    asm volatile("s_waitcnt vmcnt(12)");
    SCHEDBAR();
    BAR();

#pragma unroll 2
    for (int T = 0; T < 18; ++T) {
        const int ab = (T & 1) * 16384;
        const int bb = 32768 + (T & 1) * 16384;
        const int t2 = T + 2;
        const bool st = (t2 < 18);
        short8 a0[2][4], a1[2][4], b0[2][2], b1[2][2];

        // ---- P1: read A-lo + B-lo; MFMA q(lo,lo)
#pragma unroll
        for (int kk = 0; kk < 2; ++kk) {
#pragma unroll
            for (int mi = 0; mi < 4; ++mi)
                a0[kk][mi] = *(const short8*)&smem[ab + arow + mi * 1024 + gs[kk]];
#pragma unroll
            for (int ni = 0; ni < 2; ++ni)
                b0[kk][ni] = *(const short8*)&smem[bb + brow + ni * 1024 + gs[kk]];
        }
        SCHEDBAR();
        BAR();
        asm volatile("s_waitcnt lgkmcnt(0)");
        SCHEDBAR();
        __builtin_amdgcn_s_setprio(1);
#pragma unroll
        for (int kk = 0; kk < 2; ++kk)
#pragma unroll
            for (int mi = 0; mi < 4; ++mi)
#pragma unroll
                for (int ni = 0; ni < 2; ++ni)
                    acc[mi][ni] = __builtin_amdgcn_mfma_f32_16x16x32_bf16(a0[kk][mi], b0[kk][ni], acc[mi][ni], 0, 0, 0);
        __builtin_amdgcn_s_setprio(0);
        SCHEDBAR();
        asm volatile("s_waitcnt vmcnt(10)");
        SCHEDBAR();
        BAR();

        // ---- P2: read A-hi; stage A0,B0(T+2); MFMA q(hi,lo)
#pragma unroll
        for (int kk = 0; kk < 2; ++kk)
#pragma unroll
            for (int mi = 0; mi < 4; ++mi)
                a1[kk][mi] = *(const short8*)&smem[ab + arow + 4096 + mi * 1024 + gs[kk]];
        if (st) { stA(t2, 0); stB(t2, 0); }
        SCHEDBAR();
        BAR();
        asm volatile("s_waitcnt lgkmcnt(0)");
        SCHEDBAR();
        __builtin_amdgcn_s_setprio(1);
#pragma unroll
        for (int kk = 0; kk < 2; ++kk)
#pragma unroll
            for (int mi = 0; mi < 4; ++mi)
#pragma unroll
                for (int ni = 0; ni < 2; ++ni)
                    acc[mi + 4][ni] = __builtin_amdgcn_mfma_f32_16x16x32_bf16(a1[kk][mi], b0[kk][ni], acc[mi + 4][ni], 0, 0, 0);
        __builtin_amdgcn_s_setprio(0);
        SCHEDBAR();
        asm volatile("s_waitcnt vmcnt(12)");
        SCHEDBAR();
        BAR();

        // ---- P3: read B-hi; stage A1(T+2); MFMA q(lo,hi)
#pragma unroll
        for (int kk = 0; kk < 2; ++kk)
#pragma unroll
            for (int ni = 0; ni < 2; ++ni)
                b1[kk][ni] = *(const short8*)&smem[bb + brow + 2048 + ni * 1024 + gs[kk]];
        if (st) stA(t2, 1);
        SCHEDBAR();
        BAR();
        asm volatile("s_waitcnt lgkmcnt(0)");
        SCHEDBAR();
        __builtin_amdgcn_s_setprio(1);
#pragma unroll
        for (int kk = 0; kk < 2; ++kk)
#pragma unroll
            for (int mi = 0; mi < 4; ++mi)
#pragma unroll
                for (int ni = 0; ni < 2; ++ni)
                    acc[mi][ni + 2] = __builtin_amdgcn_mfma_f32_16x16x32_bf16(a0[kk][mi], b1[kk][ni], acc[mi][ni + 2], 0, 0, 0);
        __builtin_amdgcn_s_setprio(0);
        SCHEDBAR();
        BAR();

        // ---- P4: stage B1(T+2); MFMA q(hi,hi)
        if (st) stB(t2, 1);
        SCHEDBAR();
        BAR();
        __builtin_amdgcn_s_setprio(1);
#pragma unroll
        for (int kk = 0; kk < 2; ++kk)
#pragma unroll
            for (int mi = 0; mi < 4; ++mi)
#pragma unroll
                for (int ni = 0; ni < 2; ++ni)
                    acc[mi + 4][ni + 2] = __builtin_amdgcn_mfma_f32_16x16x32_bf16(a1[kk][mi], b1[kk][ni], acc[mi + 4][ni + 2], 0, 0, 0);
        __builtin_amdgcn_s_setprio(0);
        SCHEDBAR();
        asm volatile("s_waitcnt vmcnt(12)");
        SCHEDBAR();
        BAR();
    }

    // epilogue: col = cl, row = quad*4 + reg
#pragma unroll
    for (int mi = 0; mi < 8; ++mi) {
        long row = rowBase + wm * 128 + mi * 16 + quad * 4;
#pragma unroll
        for (int ni = 0; ni < 4; ++ni) {
            int col = colBase + wn * 64 + ni * 16 + cl;
            if (col < 1152) {
                float bv = bias[col];
#pragma unroll
                for (int r = 0; r < 4; ++r) {
                    float v = (acc[mi][ni][r] + bv) * scale;
                    if (MODE == 0) outA[(row + r) * 1152 + col] = f2bf(v);
                    else           outF[(row + r) * 1152L + col] = v;
                }
            }
        }
    }
}

// ---------------- GEMM (m97 structure), kept for the small KV projection ----------------
// MODE 1: KV projection: K -> outA [b][h][384][72] (rows 300..383 pre-zeroed);
//         V -> outB [b][h][3][72][128], m-granules XOR-swizzled by (dd&7)
template <int MODE>
__global__ __launch_bounds__(256)
void gemm_bt(const u16* __restrict__ A, const u16* __restrict__ Bt,
             const float* __restrict__ bias, float scale,
             u16* __restrict__ outA, u16* __restrict__ outB, float* __restrict__ outF,
             int M, int N, int K) {
    __shared__ u16 As[128 * 32];
    __shared__ u16 Bs[128 * 32];
    const int tid = threadIdx.x, lane = tid & 63, wave = tid >> 6;
    const int wm = wave >> 1, wn = wave & 1;
    const int quad = lane >> 4, cl = lane & 15;
    const long rowBase = (long)blockIdx.x * 128;
    const int colBase = blockIdx.y * 128;
    const int srow = lane >> 2;
    const int skc = (lane & 3) * 8;

    floatx4 acc[4][4];
#pragma unroll
    for (int i = 0; i < 4; i++)
#pragma unroll
        for (int j = 0; j < 4; j++) acc[i][j] = (floatx4){0.f, 0.f, 0.f, 0.f};

    for (int k0 = 0; k0 < K; k0 += 32) {
#pragma unroll
        for (int j = 0; j < 2; ++j) {
            int inst = wave * 2 + j;
            long r = rowBase + inst * 16 + srow;
            if (r > (long)M - 1) r = (long)M - 1;
            async16(A + r * K + k0 + skc, &As[inst * 512]);
        }
#pragma unroll
        for (int j = 0; j < 2; ++j) {
            int inst = wave * 2 + j;
            long r = colBase + inst * 16 + srow;
            async16(Bt + r * K + k0 + skc, &Bs[inst * 512]);
        }
        __syncthreads();
        short8 af[4], bf[4];
#pragma unroll
        for (int mi = 0; mi < 4; mi++)
            af[mi] = *(const short8*)&As[(wm * 64 + mi * 16 + cl) * 32 + quad * 8];
#pragma unroll
        for (int ni = 0; ni < 4; ni++)
            bf[ni] = *(const short8*)&Bs[(wn * 64 + ni * 16 + cl) * 32 + quad * 8];
#pragma unroll
        for (int mi = 0; mi < 4; mi++)
#pragma unroll
            for (int ni = 0; ni < 4; ni++)
                acc[mi][ni] = __builtin_amdgcn_mfma_f32_16x16x32_bf16(af[mi], bf[ni], acc[mi][ni], 0, 0, 0);
        __syncthreads();
    }

#pragma unroll
    for (int mi = 0; mi < 4; mi++) {
        long row0 = rowBase + wm * 64 + mi * 16 + quad * 4;
#pragma unroll
        for (int ni = 0; ni < 4; ni++) {
            int col = colBase + wn * 64 + ni * 16 + cl;
            float bv = bias[col];
#pragma unroll
            for (int r = 0; r < 4; r++) {
                long row = row0 + r;
                if (row < M) {
                    float v = (acc[mi][ni][r] + bv) * scale;
                    if (MODE == 1) {
                        int bb = (int)(row / 300);
                        int mm = (int)(row - (long)bb * 300);
                        if (col < 1152) {
                            int hh = col / 72, dd = col - hh * 72;
                            outA[((long)(bb * 16 + hh) * 384 + mm) * 72 + dd] = f2bf(v);
                        } else {
                            int c2 = col - 1152;
                            int hh = c2 / 72, dd = c2 - hh * 72;
                            int ch = mm >> 7, mc = mm & 127;
                            int g = (mc >> 3) ^ (dd & 7);
                            outB[(((long)(bb * 16 + hh) * 3 + ch) * 72 + dd) * 128 + g * 8 + (mc & 7)] = f2bf(v);
                        }
                    }
                }
            }
        }
    }
}

// ---------------- fused masked attention (unchanged) ----------------
__global__ __launch_bounds__(256, 4)
void attn_kernel(const u16* __restrict__ Q, const u16* __restrict__ K,
                 const u16* __restrict__ V, const int* __restrict__ mask,
                 u16* __restrict__ O) {
    __shared__ __align__(16) u16 smem[(18432 + 20480) / 2];
    u16* Ks = smem;
    u16* Vs = smem + 9216;

    const int tid = threadIdx.x, lane = tid & 63, wave = tid >> 6;
    const int quad = lane >> 4, cl = lane & 15;
    const int b = blockIdx.z, h = blockIdx.y, nt = blockIdx.x;
    int mb = mask[b];
    if (mb > 300) mb = 300;
    if (mb < 1) mb = 1;
    const int bh = b * 16 + h;

    const long qbase = ((long)b * 4096 + nt * 64) * 1152 + h * 72;

    const u16* qrow = Q + qbase + (long)(wave * 16 + cl) * 1152;
    short8 zero8 = {0, 0, 0, 0, 0, 0, 0, 0};
    short8 aq[3];
    aq[0] = *(const short8*)(qrow + quad * 8);
    aq[1] = *(const short8*)(qrow + 32 + quad * 8);
    aq[2] = (quad == 0) ? *(const short8*)(qrow + 64) : zero8;

    if (tid < 16) {
        unsigned fill = 0x3F803F80u;
        *(uint4*)&Vs[72 * 128 + tid * 8] = (uint4){fill, fill, fill, fill};
    }

    floatx4 oacc[5];
#pragma unroll
    for (int i = 0; i < 5; i++) oacc[i] = (floatx4){0.f, 0.f, 0.f, 0.f};

    const u16* kb = K + (long)bh * 384 * 72;
    const u16* vb = V + (long)bh * 3 * 9216;

    const int nch = (mb + 127) >> 7;
    for (int ch = 0; ch < nch; ++ch) {
        const int base = ch << 7;
        __syncthreads();

        const u16* ksrc = kb + (long)base * 72;
        for (int i = wave; i < 18; i += 4)
            async16(ksrc + i * 512 + lane * 8, Ks + i * 512);
        const u16* vsrc = vb + (long)ch * 9216;
        for (int i = wave; i < 18; i += 4)
            async16(vsrc + i * 512 + lane * 8, Vs + i * 512);
        __syncthreads();

        floatx4 sacc[8];
#pragma unroll
        for (int t = 0; t < 8; t++) sacc[t] = (floatx4){0.f, 0.f, 0.f, 0.f};
#pragma unroll
        for (int kk = 0; kk < 3; ++kk) {
#pragma unroll
            for (int t = 0; t < 8; ++t) {
                short8 bfr = *(const short8*)&Ks[(t * 16 + cl) * 72 + kk * 32 + quad * 8];
                sacc[t] = __builtin_amdgcn_mfma_f32_16x16x32_bf16(aq[kk], bfr, sacc[t], 0, 0, 0);
            }
        }
        __syncthreads();

#pragma unroll
        for (int r = 0; r < 4; ++r) {
            int prow = (wave * 16 + quad * 4 + r) * 136;
#pragma unroll
            for (int t = 0; t < 8; ++t) {
                int col = base + t * 16 + cl;
                float p = (col < mb) ? __expf(sacc[t][r]) : 0.f;
                unsigned pb = f2bf(p);
                unsigned ob = __shfl_xor(pb, 1);
                if (!(lane & 1))
                    *(unsigned*)&Ks[prow + t * 16 + cl] = pb | (ob << 16);
            }
        }

#pragma unroll
        for (int kk = 0; kk < 4; ++kk) {
            short8 pf = *(const short8*)&Ks[(wave * 16 + cl) * 136 + kk * 32 + quad * 8];
#pragma unroll
            for (int dt = 0; dt < 5; ++dt) {
                int dd = dt * 16 + cl;
                short8 vf = *(const short8*)&Vs[dd * 128 + (((kk * 4 + quad) ^ (dd & 7)) << 3)];
                oacc[dt] = __builtin_amdgcn_mfma_f32_16x16x32_bf16(pf, vf, oacc[dt], 0, 0, 0);
            }
        }
    }

#pragma unroll
    for (int r = 0; r < 4; r++) {
        float l = __shfl(oacc[4][r], (lane & 48) + 8);
        float inv = 1.0f / l;
        int row = wave * 16 + quad * 4 + r;
#pragma unroll
        for (int dt = 0; dt < 5; dt++) {
            int dd = dt * 16 + cl;
            if (dd < 72) O[qbase + (long)row * 1152 + dd] = f2bf(oacc[dt][r] * inv);
        }
    }
}

extern "C" void kernel_launch(void* const* d_in, const int* in_sizes, int n_in,
                              void* d_out, int out_size, void* d_ws, size_t ws_size,
                              hipStream_t stream) {
    const float* x    = (const float*)d_in[0];
    const float* cond = (const float*)d_in[1];
    const int*   mask = (const int*)d_in[2];
    const float* wq   = (const float*)d_in[3];
    const float* bq   = (const float*)d_in[4];
    const float* wkv  = (const float*)d_in[5];
    const float* bkv  = (const float*)d_in[6];
    const float* wp   = (const float*)d_in[7];
    const float* bp   = (const float*)d_in[8];

    char* ws = (char*)d_ws;
    u16* xb    = (u16*)(ws);                  // 75,497,472  x bf16 / attn out bf16
    u16* condb = (u16*)(ws + 75497472ll);     //  5,529,600
    u16* wkvT  = (u16*)(ws + 81027072ll);     //  5,308,416
    u16* qbuf  = (u16*)(ws + 86335488ll);     // 75,497,472
    u16* kbuf  = (u16*)(ws + 161832960ll);    //  7,077,888   K [b][h][384][72], pads zeroed
    u16* vbuf  = (u16*)(ws + 168910848ll);    //  7,077,888   V [b][h][3][72][128] swizzled
    // aliases into the kbuf/vbuf region (time-disjoint), 1280x1152 padded:
    u16* wqT   = (u16*)(ws + 161832960ll);    //  2,949,120   dead before fill_zero
    u16* wpT   = (u16*)(ws + 161832960ll);    //  2,949,120   written after attn
    if (ws_size < 175988736ull) return;

    static bool s_attr = false;
    if (!s_attr) {
        hipFuncSetAttribute((const void*)gemm8p<0>, hipFuncAttributeMaxDynamicSharedMemorySize, 131072);
        hipFuncSetAttribute((const void*)gemm8p<2>, hipFuncAttributeMaxDynamicSharedMemorySize, 131072);
        s_attr = true;
    }

    cast_bf16_kernel<<<18432, 256, 0, stream>>>(x, xb, 4718592ll);
    cast_bf16_kernel<<<1350, 256, 0, stream>>>(cond, condb, 345600ll);

    // wqT: zero pad rows 1152..1279, then transpose wq into rows 0..1151
    fill_zero<<<72, 256, 0, stream>>>((uint4*)((char*)wqT + 2654208ll), 18432);
    transpose_cast<<<dim3(36, 36), dim3(32, 8), 0, stream>>>(wq, wqT, 1152, 1152);
    transpose_cast<<<dim3(72, 36), dim3(32, 8), 0, stream>>>(wkv, wkvT, 1152, 2304);

    // Q = (x@wq + bq) * 1/sqrt(72), bf16 (8-phase GEMM; reads wqT which aliases kbuf)
    gemm8p<0><<<640, 512, 131072, stream>>>(xb, wqT, bq, 0.11785113019775793f, qbuf, nullptr);

    // zero K/V pad regions (kbuf+vbuf, 14,155,776 B) so attn's padded chunks stay finite
    fill_zero<<<3456, 256, 0, stream>>>((uint4*)kbuf, 884736);
    // KV = cond@wkv + bkv -> K padded / V chunk-swizzled, bf16
    gemm_bt<1><<<dim3(19, 18), 256, 0, stream>>>(condb, wkvT, bkv, 1.0f,
                                                 kbuf, vbuf, nullptr, 2400, 2304, 1152);
    // attention -> bf16, into xb region
    attn_kernel<<<dim3(64, 16, 8), 256, 0, stream>>>(qbuf, kbuf, vbuf, mask, xb);

    // wpT (aliases now-dead kbuf): zero pads + transpose
    fill_zero<<<72, 256, 0, stream>>>((uint4*)((char*)wpT + 2654208ll), 18432);
    transpose_cast<<<dim3(36, 36), dim3(32, 8), 0, stream>>>(wp, wpT, 1152, 1152);
    // out = attn@wp + bp, fp32 (8-phase GEMM)
    gemm8p<2><<<640, 512, 131072, stream>>>(xb, wpT, bp, 1.0f, nullptr, (float*)d_out);
}

// Round 5
// 616.796 us; speedup vs baseline: 1.0658x; 1.0658x over previous
//
#include <hip/hip_runtime.h>
#include <cstdint>

typedef unsigned short u16;
typedef __attribute__((ext_vector_type(8))) short short8;
typedef __attribute__((ext_vector_type(4))) float floatx4;

#define BAR()      __builtin_amdgcn_s_barrier()
#define SCHEDBAR() __builtin_amdgcn_sched_barrier(0)

__device__ __forceinline__ u16 f2bf(float f) {
    unsigned u = __float_as_uint(f);
    u += 0x7FFFu + ((u >> 16) & 1u);
    return (u16)(u >> 16);
}

__device__ __forceinline__ void async16(const void* g, void* l) {
    __builtin_amdgcn_global_load_lds(
        (const __attribute__((address_space(1))) unsigned*)g,
        (__attribute__((address_space(3))) unsigned*)l, 16, 0, 0);
}

// ---------------- cast fp32 -> bf16, 8 elems/thread ----------------
__global__ void cast_bf16_kernel(const float* __restrict__ in, u16* __restrict__ out, long n8) {
    long i = (long)blockIdx.x * 256 + threadIdx.x;
    if (i >= n8) return;
    const float4* p = (const float4*)in;
    float4 a = p[i * 2], b = p[i * 2 + 1];
    uint4 o;
    o.x = f2bf(a.x) | ((unsigned)f2bf(a.y) << 16);
    o.y = f2bf(a.z) | ((unsigned)f2bf(a.w) << 16);
    o.z = f2bf(b.x) | ((unsigned)f2bf(b.y) << 16);
    o.w = f2bf(b.z) | ((unsigned)f2bf(b.w) << 16);
    ((uint4*)out)[i] = o;
}

// ---------------- zero fill (uint4 granularity) ----------------
__global__ void fill_zero(uint4* __restrict__ p, int n) {
    int i = blockIdx.x * 256 + threadIdx.x;
    if (i < n) p[i] = (uint4){0u, 0u, 0u, 0u};
}

// ---------------- transpose + cast: W[K][N] -> Wt[N][K] bf16 ----------------
__global__ void transpose_cast(const float* __restrict__ W, u16* __restrict__ Wt, int K, int N) {
    __shared__ float tile[32][33];
    int bx = blockIdx.x * 32, by = blockIdx.y * 32;
    int tx = threadIdx.x, ty = threadIdx.y;
#pragma unroll
    for (int i = 0; i < 32; i += 8)
        tile[ty + i][tx] = W[(long)(by + ty + i) * N + bx + tx];
    __syncthreads();
#pragma unroll
    for (int i = 0; i < 32; i += 8)
        Wt[(long)(bx + ty + i) * K + by + tx] = f2bf(tile[tx][ty + i]);
}

// ---------------- gemm8p helpers ----------------
__device__ __forceinline__ void rd8(short8 (&a)[2][4], const u16* sm, int base, int g0, int g1) {
#pragma unroll
    for (int mi = 0; mi < 4; ++mi) {
        a[0][mi] = *(const short8*)&sm[base + mi * 1024 + g0];
        a[1][mi] = *(const short8*)&sm[base + mi * 1024 + g1];
    }
}
__device__ __forceinline__ void rd6(short8 (&b)[2][3], const u16* sm, int base, int g0, int g1) {
#pragma unroll
    for (int ni = 0; ni < 3; ++ni) {
        b[0][ni] = *(const short8*)&sm[base + ni * 1024 + g0];
        b[1][ni] = *(const short8*)&sm[base + ni * 1024 + g1];
    }
}
__device__ __forceinline__ void mfma24(floatx4 (&ah)[4][3], const short8 (&a)[2][4], const short8 (&b)[2][3]) {
#pragma unroll
    for (int kk = 0; kk < 2; ++kk)
#pragma unroll
        for (int mi = 0; mi < 4; ++mi)
#pragma unroll
            for (int ni = 0; ni < 3; ++ni)
                ah[mi][ni] = __builtin_amdgcn_mfma_f32_16x16x32_bf16(a[kk][mi], b[kk][ni], ah[mi][ni], 0, 0, 0);
}

// ============ 2-phase 256x192 GEMM (T1+T2+T3+T4+T5), M=32768 N=1152 K=1152 ============
// C[M][1152] = A[M][1152] @ Bt[1152][1152]^T. No N-padding; grid 128x6 = 768 = 3x256
// exactly (zero tail). 8 waves (2M x 4N), per-wave 128x48 (acc[2][4][3]). BK=64,
// LDS = A 2x32KB + B 2x24KB = 112 KiB dynamic, 1 block/CU.
// Per K-tile: P1 {rd a0(8)+b(6); stage A-hi(T+1) [depth-1]; BAR; lgkm0; 24 MFMA (mi-lo);
// vmcnt(7); BAR}  P2 {rd a1(8); stage A-lo(T+2)+B(T+2) [depth-2]; BAR; lgkm0; 24 MFMA
// (mi-hi, reusing b regs); vmcnt(7); BAR}.
// Hazard ledger (per-wave: P1 issues 2 loads, P2 issues 5):
//  - gate end-P1(T): A-hi(T) issued P1(T-1); issued-after = P2(T-1) 5 + P1(T) 2 = 7.
//  - gate end-P2(T): A-lo/B(T+1) issued P2(T-1); issued-after = P1(T) 2 + P2(T) 5 = 7.
//  - overwrite-safety: A-hi(T+1) targets buffer (T+1)&1 whose hi-rows were drained at
//    end-P2(T-1) BAR; A-lo(T+2)/B(T+2) target rows last ds_read in P1(T), drained by
//    every wave's lgkm0 before end-P1 BAR; A-lo rows disjoint from P2's a1 rows.
//  - tail (T=16,17 peeled): gates tighten 7 -> 2 -> 0 as staging stops.
// MODE 0: bf16 out, (acc+bias)*scale.  MODE 2: fp32 out.
template <int MODE>
__global__ __launch_bounds__(512, 2)
void gemm8p(const u16* __restrict__ A, const u16* __restrict__ Bt,
            const float* __restrict__ bias, float scale,
            u16* __restrict__ outA, float* __restrict__ outF) {
    extern __shared__ u16 smem[];   // u16 units: A bufs [0,32768); B bufs [32768,57344)
    const int K = 1152;
    const int tid = threadIdx.x, lane = tid & 63, wave = tid >> 6;
    const int quad = lane >> 4, cl = lane & 15;
    const int wm = wave >> 2, wn = wave & 3;
    const int l3 = lane >> 3, l7 = lane & 7;
    const int w8 = wave * 8;

    // T1: bijective XCD swizzle (768 = 8*96); within-XCD contiguous = 16 row-panels x 6
    int bid = blockIdx.x;
    int swz = (bid & 7) * 96 + (bid >> 3);
    int colTile = swz % 6, rowTile = swz / 6;
    const long rowBase = (long)rowTile * 256;
    const int colBase = colTile * 192;

    // staging source (pre-swizzled granule: LDS granule l7 at row r0+l3 holds logical
    // granule (l7 ^ ((r0+l3)&7)) = (l7^l3) since r0 % 8 == 0)
    const int sg = (l7 ^ l3) * 8;
    const u16* pA = A + (rowBase + l3) * (long)K + sg;
    const u16* pB = Bt + ((long)colBase + l3) * (long)K + sg;

    auto stA = [&](int Ts, int r0) {   // stages rows [r0, r0+8) of tile Ts
        async16(pA + (long)r0 * K + Ts * 64, &smem[(Ts & 1) * 16384 + r0 * 64]);
    };
    auto stB = [&](int Ts, int r0) {
        async16(pB + (long)r0 * K + Ts * 64, &smem[32768 + (Ts & 1) * 12288 + r0 * 64]);
    };

    // fragment read offsets (T2 swizzle: granule = (kk*4+quad) ^ (row&7), row&7 == cl&7)
    const int arow = wm * 8192 + cl * 64;
    const int brow = wn * 3072 + cl * 64;
    const int gs0 = (quad ^ (cl & 7)) * 8;
    const int gs1 = ((4 + quad) ^ (cl & 7)) * 8;

    floatx4 acc[2][4][3];
#pragma unroll
    for (int h = 0; h < 2; ++h)
#pragma unroll
        for (int i = 0; i < 4; ++i)
#pragma unroll
            for (int j = 0; j < 3; ++j) acc[h][i][j] = (floatx4){0.f, 0.f, 0.f, 0.f};

    short8 a0[2][4], a1[2][4], bf[2][3];

    // prologue: A-lo(0),B(0) [5] ; A-hi(0) [2] ; A-lo(1),B(1) [5]
    stA(0, w8); stA(0, 128 + w8);
    stB(0, w8); stB(0, 64 + w8); stB(0, 128 + w8);
    stA(0, 64 + w8); stA(0, 192 + w8);
    stA(1, w8); stA(1, 128 + w8);
    stB(1, w8); stB(1, 64 + w8); stB(1, 128 + w8);
    SCHEDBAR();
    asm volatile("s_waitcnt vmcnt(7)");   // A-lo(0),B(0) landed (7 issued after)
    SCHEDBAR();
    BAR();

#pragma unroll 2
    for (int T = 0; T < 16; ++T) {
        const int ab = (T & 1) * 16384;
        const int bb = 32768 + (T & 1) * 12288;
        // ---- P1: read A-lo + B; stage A-hi(T+1); MFMA mi-lo
        rd8(a0, smem, ab + arow, gs0, gs1);
        rd6(bf, smem, bb + brow, gs0, gs1);
        stA(T + 1, 64 + w8); stA(T + 1, 192 + w8);
        SCHEDBAR(); BAR();
        asm volatile("s_waitcnt lgkmcnt(0)"); SCHEDBAR();
        __builtin_amdgcn_s_setprio(1);
        mfma24(acc[0], a0, bf);
        __builtin_amdgcn_s_setprio(0);
        SCHEDBAR();
        asm volatile("s_waitcnt vmcnt(7)"); SCHEDBAR(); BAR();
        // ---- P2: read A-hi; stage A-lo(T+2)+B(T+2); MFMA mi-hi (b regs reused)
        rd8(a1, smem, ab + arow + 4096, gs0, gs1);
        stA(T + 2, w8); stA(T + 2, 128 + w8);
        stB(T + 2, w8); stB(T + 2, 64 + w8); stB(T + 2, 128 + w8);
        SCHEDBAR(); BAR();
        asm volatile("s_waitcnt lgkmcnt(0)"); SCHEDBAR();
        __builtin_amdgcn_s_setprio(1);
        mfma24(acc[1], a1, bf);
        __builtin_amdgcn_s_setprio(0);
        SCHEDBAR();
        asm volatile("s_waitcnt vmcnt(7)"); SCHEDBAR(); BAR();
    }

    // ---- tail T=16 (ab=0): P1 stages A-hi(17) only; gates 7 then 2
    {
        const int ab = 0, bb = 32768;
        rd8(a0, smem, ab + arow, gs0, gs1);
        rd6(bf, smem, bb + brow, gs0, gs1);
        stA(17, 64 + w8); stA(17, 192 + w8);
        SCHEDBAR(); BAR();
        asm volatile("s_waitcnt lgkmcnt(0)"); SCHEDBAR();
        __builtin_amdgcn_s_setprio(1);
        mfma24(acc[0], a0, bf);
        __builtin_amdgcn_s_setprio(0);
        SCHEDBAR();
        asm volatile("s_waitcnt vmcnt(7)"); SCHEDBAR(); BAR();
        rd8(a1, smem, ab + arow + 4096, gs0, gs1);
        SCHEDBAR(); BAR();
        asm volatile("s_waitcnt lgkmcnt(0)"); SCHEDBAR();
        __builtin_amdgcn_s_setprio(1);
        mfma24(acc[1], a1, bf);
        __builtin_amdgcn_s_setprio(0);
        SCHEDBAR();
        asm volatile("s_waitcnt vmcnt(2)"); SCHEDBAR(); BAR();
    }
    // ---- tail T=17 (ab=16384): no staging; gate 0 before A-hi read
    {
        const int ab = 16384, bb = 32768 + 12288;
        rd8(a0, smem, ab + arow, gs0, gs1);
        rd6(bf, smem, bb + brow, gs0, gs1);
        SCHEDBAR(); BAR();
        asm volatile("s_waitcnt lgkmcnt(0)"); SCHEDBAR();
        __builtin_amdgcn_s_setprio(1);
        mfma24(acc[0], a0, bf);
        __builtin_amdgcn_s_setprio(0);
        SCHEDBAR();
        asm volatile("s_waitcnt vmcnt(0)"); SCHEDBAR(); BAR();
        rd8(a1, smem, ab + arow + 4096, gs0, gs1);
        SCHEDBAR();
        asm volatile("s_waitcnt lgkmcnt(0)"); SCHEDBAR();
        __builtin_amdgcn_s_setprio(1);
        mfma24(acc[1], a1, bf);
        __builtin_amdgcn_s_setprio(0);
        SCHEDBAR();
    }

    // epilogue: col = cl, row = quad*4 + reg (m89/m91-verified)
#pragma unroll
    for (int h = 0; h < 2; ++h)
#pragma unroll
        for (int mi = 0; mi < 4; ++mi) {
            long row = rowBase + wm * 128 + (h * 4 + mi) * 16 + quad * 4;
#pragma unroll
            for (int ni = 0; ni < 3; ++ni) {
                int col = colBase + wn * 48 + ni * 16 + cl;
                float bv = bias[col];
#pragma unroll
                for (int r = 0; r < 4; ++r) {
                    float v = (acc[h][mi][ni][r] + bv) * scale;
                    if (MODE == 0) outA[(row + r) * 1152 + col] = f2bf(v);
                    else           outF[(row + r) * 1152L + col] = v;
                }
            }
        }
}

// ---------------- GEMM (m97 structure), kept for the small KV projection ----------------
// MODE 1: KV projection: K -> outA [b][h][384][72] (rows 300..383 pre-zeroed);
//         V -> outB [b][h][3][72][128], m-granules XOR-swizzled by (dd&7)
template <int MODE>
__global__ __launch_bounds__(256)
void gemm_bt(const u16* __restrict__ A, const u16* __restrict__ Bt,
             const float* __restrict__ bias, float scale,
             u16* __restrict__ outA, u16* __restrict__ outB, float* __restrict__ outF,
             int M, int N, int K) {
    __shared__ u16 As[128 * 32];
    __shared__ u16 Bs[128 * 32];
    const int tid = threadIdx.x, lane = tid & 63, wave = tid >> 6;
    const int wm = wave >> 1, wn = wave & 1;
    const int quad = lane >> 4, cl = lane & 15;
    const long rowBase = (long)blockIdx.x * 128;
    const int colBase = blockIdx.y * 128;
    const int srow = lane >> 2;
    const int skc = (lane & 3) * 8;

    floatx4 acc[4][4];
#pragma unroll
    for (int i = 0; i < 4; i++)
#pragma unroll
        for (int j = 0; j < 4; j++) acc[i][j] = (floatx4){0.f, 0.f, 0.f, 0.f};

    for (int k0 = 0; k0 < K; k0 += 32) {
#pragma unroll
        for (int j = 0; j < 2; ++j) {
            int inst = wave * 2 + j;
            long r = rowBase + inst * 16 + srow;
            if (r > (long)M - 1) r = (long)M - 1;
            async16(A + r * K + k0 + skc, &As[inst * 512]);
        }
#pragma unroll
        for (int j = 0; j < 2; ++j) {
            int inst = wave * 2 + j;
            long r = colBase + inst * 16 + srow;
            async16(Bt + r * K + k0 + skc, &Bs[inst * 512]);
        }
        __syncthreads();
        short8 af[4], bfr[4];
#pragma unroll
        for (int mi = 0; mi < 4; mi++)
            af[mi] = *(const short8*)&As[(wm * 64 + mi * 16 + cl) * 32 + quad * 8];
#pragma unroll
        for (int ni = 0; ni < 4; ni++)
            bfr[ni] = *(const short8*)&Bs[(wn * 64 + ni * 16 + cl) * 32 + quad * 8];
#pragma unroll
        for (int mi = 0; mi < 4; mi++)
#pragma unroll
            for (int ni = 0; ni < 4; ni++)
                acc[mi][ni] = __builtin_amdgcn_mfma_f32_16x16x32_bf16(af[mi], bfr[ni], acc[mi][ni], 0, 0, 0);
        __syncthreads();
    }

#pragma unroll
    for (int mi = 0; mi < 4; mi++) {
        long row0 = rowBase + wm * 64 + mi * 16 + quad * 4;
#pragma unroll
        for (int ni = 0; ni < 4; ni++) {
            int col = colBase + wn * 64 + ni * 16 + cl;
            float bv = bias[col];
#pragma unroll
            for (int r = 0; r < 4; r++) {
                long row = row0 + r;
                if (row < M) {
                    float v = (acc[mi][ni][r] + bv) * scale;
                    if (MODE == 1) {
                        int bb = (int)(row / 300);
                        int mm = (int)(row - (long)bb * 300);
                        if (col < 1152) {
                            int hh = col / 72, dd = col - hh * 72;
                            outA[((long)(bb * 16 + hh) * 384 + mm) * 72 + dd] = f2bf(v);
                        } else {
                            int c2 = col - 1152;
                            int hh = c2 / 72, dd = c2 - hh * 72;
                            int ch = mm >> 7, mc = mm & 127;
                            int g = (mc >> 3) ^ (dd & 7);
                            outB[(((long)(bb * 16 + hh) * 3 + ch) * 72 + dd) * 128 + g * 8 + (mc & 7)] = f2bf(v);
                        }
                    }
                }
            }
        }
    }
}

// ---------------- fused masked attention (unchanged) ----------------
__global__ __launch_bounds__(256, 4)
void attn_kernel(const u16* __restrict__ Q, const u16* __restrict__ K,
                 const u16* __restrict__ V, const int* __restrict__ mask,
                 u16* __restrict__ O) {
    __shared__ __align__(16) u16 smem[(18432 + 20480) / 2];
    u16* Ks = smem;
    u16* Vs = smem + 9216;

    const int tid = threadIdx.x, lane = tid & 63, wave = tid >> 6;
    const int quad = lane >> 4, cl = lane & 15;
    const int b = blockIdx.z, h = blockIdx.y, nt = blockIdx.x;
    int mb = mask[b];
    if (mb > 300) mb = 300;
    if (mb < 1) mb = 1;
    const int bh = b * 16 + h;

    const long qbase = ((long)b * 4096 + nt * 64) * 1152 + h * 72;

    const u16* qrow = Q + qbase + (long)(wave * 16 + cl) * 1152;
    short8 zero8 = {0, 0, 0, 0, 0, 0, 0, 0};
    short8 aq[3];
    aq[0] = *(const short8*)(qrow + quad * 8);
    aq[1] = *(const short8*)(qrow + 32 + quad * 8);
    aq[2] = (quad == 0) ? *(const short8*)(qrow + 64) : zero8;

    if (tid < 16) {
        unsigned fill = 0x3F803F80u;
        *(uint4*)&Vs[72 * 128 + tid * 8] = (uint4){fill, fill, fill, fill};
    }

    floatx4 oacc[5];
#pragma unroll
    for (int i = 0; i < 5; i++) oacc[i] = (floatx4){0.f, 0.f, 0.f, 0.f};

    const u16* kb = K + (long)bh * 384 * 72;
    const u16* vb = V + (long)bh * 3 * 9216;

    const int nch = (mb + 127) >> 7;
    for (int ch = 0; ch < nch; ++ch) {
        const int base = ch << 7;
        __syncthreads();

        const u16* ksrc = kb + (long)base * 72;
        for (int i = wave; i < 18; i += 4)
            async16(ksrc + i * 512 + lane * 8, Ks + i * 512);
        const u16* vsrc = vb + (long)ch * 9216;
        for (int i = wave; i < 18; i += 4)
            async16(vsrc + i * 512 + lane * 8, Vs + i * 512);
        __syncthreads();

        floatx4 sacc[8];
#pragma unroll
        for (int t = 0; t < 8; t++) sacc[t] = (floatx4){0.f, 0.f, 0.f, 0.f};
#pragma unroll
        for (int kk = 0; kk < 3; ++kk) {
#pragma unroll
            for (int t = 0; t < 8; ++t) {
                short8 bfr = *(const short8*)&Ks[(t * 16 + cl) * 72 + kk * 32 + quad * 8];
                sacc[t] = __builtin_amdgcn_mfma_f32_16x16x32_bf16(aq[kk], bfr, sacc[t], 0, 0, 0);
            }
        }
        __syncthreads();

#pragma unroll
        for (int r = 0; r < 4; ++r) {
            int prow = (wave * 16 + quad * 4 + r) * 136;
#pragma unroll
            for (int t = 0; t < 8; ++t) {
                int col = base + t * 16 + cl;
                float p = (col < mb) ? __expf(sacc[t][r]) : 0.f;
                unsigned pb = f2bf(p);
                unsigned ob = __shfl_xor(pb, 1);
                if (!(lane & 1))
                    *(unsigned*)&Ks[prow + t * 16 + cl] = pb | (ob << 16);
            }
        }

#pragma unroll
        for (int kk = 0; kk < 4; ++kk) {
            short8 pf = *(const short8*)&Ks[(wave * 16 + cl) * 136 + kk * 32 + quad * 8];
#pragma unroll
            for (int dt = 0; dt < 5; ++dt) {
                int dd = dt * 16 + cl;
                short8 vf = *(const short8*)&Vs[dd * 128 + (((kk * 4 + quad) ^ (dd & 7)) << 3)];
                oacc[dt] = __builtin_amdgcn_mfma_f32_16x16x32_bf16(pf, vf, oacc[dt], 0, 0, 0);
            }
        }
    }

#pragma unroll
    for (int r = 0; r < 4; r++) {
        float l = __shfl(oacc[4][r], (lane & 48) + 8);
        float inv = 1.0f / l;
        int row = wave * 16 + quad * 4 + r;
#pragma unroll
        for (int dt = 0; dt < 5; dt++) {
            int dd = dt * 16 + cl;
            if (dd < 72) O[qbase + (long)row * 1152 + dd] = f2bf(oacc[dt][r] * inv);
        }
    }
}

extern "C" void kernel_launch(void* const* d_in, const int* in_sizes, int n_in,
                              void* d_out, int out_size, void* d_ws, size_t ws_size,
                              hipStream_t stream) {
    const float* x    = (const float*)d_in[0];
    const float* cond = (const float*)d_in[1];
    const int*   mask = (const int*)d_in[2];
    const float* wq   = (const float*)d_in[3];
    const float* bq   = (const float*)d_in[4];
    const float* wkv  = (const float*)d_in[5];
    const float* bkv  = (const float*)d_in[6];
    const float* wp   = (const float*)d_in[7];
    const float* bp   = (const float*)d_in[8];

    char* ws = (char*)d_ws;
    u16* xb    = (u16*)(ws);                  // 75,497,472  x bf16 / attn out bf16
    u16* condb = (u16*)(ws + 75497472ll);     //  5,529,600
    u16* wkvT  = (u16*)(ws + 81027072ll);     //  5,308,416
    u16* qbuf  = (u16*)(ws + 86335488ll);     // 75,497,472
    u16* kbuf  = (u16*)(ws + 161832960ll);    //  7,077,888   K [b][h][384][72], pads zeroed
    u16* vbuf  = (u16*)(ws + 168910848ll);    //  7,077,888   V [b][h][3][72][128] swizzled
    // aliases into the kbuf/vbuf region (time-disjoint), 1152x1152:
    u16* wqT   = (u16*)(ws + 161832960ll);    //  2,654,208   dead before fill_zero
    u16* wpT   = (u16*)(ws + 161832960ll);    //  2,654,208   written after attn
    if (ws_size < 175988736ull) return;

    static bool s_attr = false;
    if (!s_attr) {
        hipFuncSetAttribute((const void*)gemm8p<0>, hipFuncAttributeMaxDynamicSharedMemorySize, 114688);
        hipFuncSetAttribute((const void*)gemm8p<2>, hipFuncAttributeMaxDynamicSharedMemorySize, 114688);
        s_attr = true;
    }

    cast_bf16_kernel<<<18432, 256, 0, stream>>>(x, xb, 4718592ll);
    cast_bf16_kernel<<<1350, 256, 0, stream>>>(cond, condb, 345600ll);

    transpose_cast<<<dim3(36, 36), dim3(32, 8), 0, stream>>>(wq, wqT, 1152, 1152);
    transpose_cast<<<dim3(72, 36), dim3(32, 8), 0, stream>>>(wkv, wkvT, 1152, 2304);

    // Q = (x@wq + bq) * 1/sqrt(72), bf16 (2-phase 256x192 GEMM; wqT aliases kbuf)
    gemm8p<0><<<768, 512, 114688, stream>>>(xb, wqT, bq, 0.11785113019775793f, qbuf, nullptr);

    // zero K/V pad regions (kbuf+vbuf, 14,155,776 B) so attn's padded chunks stay finite
    fill_zero<<<3456, 256, 0, stream>>>((uint4*)kbuf, 884736);
    // KV = cond@wkv + bkv -> K padded / V chunk-swizzled, bf16
    gemm_bt<1><<<dim3(19, 18), 256, 0, stream>>>(condb, wkvT, bkv, 1.0f,
                                                 kbuf, vbuf, nullptr, 2400, 2304, 1152);
    // attention -> bf16, into xb region
    attn_kernel<<<dim3(64, 16, 8), 256, 0, stream>>>(qbuf, kbuf, vbuf, mask, xb);

    // wpT (aliases now-dead kbuf)
    transpose_cast<<<dim3(36, 36), dim3(32, 8), 0, stream>>>(wp, wpT, 1152, 1152);
    // out = attn@wp + bp, fp32
    gemm8p<2><<<768, 512, 114688, stream>>>(xb, wpT, bp, 1.0f, nullptr, (float*)d_out);
}